// Round 10
// baseline (517.648 us; speedup 1.0000x reference)
//
#include <hip/hip_runtime.h>

// ---------------------------------------------------------------------------
// GCN 3-layer forward. R7 structure (separate kernels; fusion experiments
// R8/R9 refuted by counters) + two-edges-per-wave gather + prep folded into
// init. d_ws layout (ws proven >= 119.2 MB):
//   [0)      packed: N u64 {hi=count, lo=fixed24 sum(ew)}   (800 KB)
//   [1 MB)   dis: N floats
//   [1.5 MB) flag: 1 int;  [1.5MB+4K) bsums: up to 1024 ints
//   [1.6 MB) row_start: (N+1) ints
//   [2.5 MB) csr: E x int2 {src, norm-as-int}  (12.8 MB, ends 15.3 MB)
//   [15.5MB) Wt1 bf16 [128][128]; Wt2; Wt3 [64][128]
//   [16 MB)  bufA: N*128 bf16 xw (25.6 MB)
//   [42 MB)  hbf: N*128 bf16 (x_bf16, then h1_bf16, then h2_bf16)
//   [96 MB)  eseq: E ints (6.4 MB)
// ---------------------------------------------------------------------------

typedef __attribute__((ext_vector_type(8))) short bf16x8;
typedef __attribute__((ext_vector_type(4))) float f32x4;

__device__ inline unsigned short f2bf(float f) {   // RNE f32 -> bf16
  unsigned int u = __float_as_uint(f);
  u += 0x7fffu + ((u >> 16) & 1u);
  return (unsigned short)(u >> 16);
}
__device__ inline float bflo(unsigned int u) { return __uint_as_float(u << 16); }
__device__ inline float bfhi(unsigned int u) { return __uint_as_float(u & 0xffff0000u); }

// Fused init: block 0 detects int64 edge layout; blocks [0,128) zero packed;
// blocks [128,288) transpose+convert W1/W2/W3; blocks [288,..) convert x.
__global__ __launch_bounds__(256)
void init_prep(const int* __restrict__ ei, int* __restrict__ flag,
               int* __restrict__ pz, int nz,
               const float* __restrict__ W1, const float* __restrict__ W2,
               const float* __restrict__ W3, unsigned short* __restrict__ Wt1,
               unsigned short* __restrict__ Wt2, unsigned short* __restrict__ Wt3,
               const float* __restrict__ x, unsigned short* __restrict__ xbf,
               long long n4) {
  const int r = blockIdx.x;
  if (r == 0) {
    __shared__ int nonzero;
    if (threadIdx.x == 0) nonzero = 0;
    __syncthreads();
    int acc = 0;
#pragma unroll
    for (int it = 0; it < 8; ++it) acc |= ei[2 * (threadIdx.x + (it << 8)) + 1];
    if (acc != 0) atomicOr(&nonzero, 1);
    __syncthreads();
    if (threadIdx.x == 0) flag[0] = (nonzero == 0) ? 1 : 0;
  }
  if (r < 128) {
    int i = r * 256 + threadIdx.x;
    for (; i < nz; i += 128 * 256) pz[i] = 0;
    return;
  }
  if (r < 288) {
    const int idx = (r - 128) * 256 + threadIdx.x;
    if (idx < 16384) {
      const int m = idx >> 7, k = idx & 127;
      Wt1[idx] = f2bf(W1[k * 128 + m]);
    } else if (idx < 32768) {
      const int l = idx - 16384;
      const int m = l >> 7, k = l & 127;
      Wt2[l] = f2bf(W2[k * 128 + m]);
    } else if (idx < 40960) {
      const int l = idx - 32768;
      const int m = l >> 7, k = l & 127;
      Wt3[l] = f2bf(W3[k * 64 + m]);
    }
    return;
  }
  long long i = (long long)(r - 288) * 256 + threadIdx.x;
  const long long stride = (long long)(gridDim.x - 288) * 256;
  for (; i < n4; i += stride) {
    const float4 v = ((const float4*)x)[i];
    ushort4 o;
    o.x = f2bf(v.x); o.y = f2bf(v.y); o.z = f2bf(v.z); o.w = f2bf(v.w);
    ((ushort4*)xbf)[i] = o;
  }
}

// One packed u64 atomic per edge: hi += 1 (count), lo += ew * 2^24 (deg).
__global__ void count_deg_pack(const int* __restrict__ ei, const int* __restrict__ flag,
                               const float* __restrict__ ew,
                               unsigned long long* __restrict__ packed,
                               int* __restrict__ eseq, int E) {
  const int e = blockIdx.x * blockDim.x + threadIdx.x;
  if (e >= E) return;
  const int use64 = flag[0];
  const int d = use64 ? ei[2 * (E + e)] : ei[E + e];
  const unsigned int fx = (unsigned int)(ew[e] * 16777216.0f);  // 2^24 fixed
  const unsigned long long old =
      atomicAdd(&packed[d], (1ULL << 32) | (unsigned long long)fx);
  eseq[e] = (int)(old >> 32);
}

// ---- 3-phase device-wide exclusive scan over hi words ----
__global__ __launch_bounds__(256)
void scan_phase1(const unsigned long long* __restrict__ packed,
                 int* __restrict__ bsums, int N) {
  __shared__ int red[256];
  const int t = threadIdx.x;
  const int base = blockIdx.x * 1024 + t * 4;
  int s = 0;
#pragma unroll
  for (int j = 0; j < 4; ++j) {
    const int idx = base + j;
    if (idx < N) s += (int)(packed[idx] >> 32);
  }
  red[t] = s;
  __syncthreads();
  for (int off = 128; off > 0; off >>= 1) {
    if (t < off) red[t] += red[t + off];
    __syncthreads();
  }
  if (t == 0) bsums[blockIdx.x] = red[0];
}

__global__ __launch_bounds__(1024)
void scan_phase2(int* __restrict__ bsums, int* __restrict__ row_start, int B, int N) {
  __shared__ int s[1024];
  const int t = threadIdx.x;
  const int v = (t < B) ? bsums[t] : 0;
  s[t] = v;
  __syncthreads();
  for (int off = 1; off < 1024; off <<= 1) {
    const int add = (t >= off) ? s[t - off] : 0;
    __syncthreads();
    s[t] += add;
    __syncthreads();
  }
  if (t < B) bsums[t] = s[t] - v;
  if (t == B - 1) row_start[N] = s[t];
}

// Phase 3 + dis = rsqrt(deg+1) fused.
__global__ __launch_bounds__(256)
void scan_phase3_dis(const unsigned long long* __restrict__ packed,
                     const int* __restrict__ bsums, int* __restrict__ row_start,
                     float* __restrict__ dis, int N) {
  __shared__ int tsum[256];
  const int t = threadIdx.x;
  const int base = blockIdx.x * 1024 + t * 4;
  unsigned long long pk[4];
  int v[4];
#pragma unroll
  for (int j = 0; j < 4; ++j) {
    pk[j] = (base + j < N) ? packed[base + j] : 0ULL;
    v[j] = (int)(pk[j] >> 32);
  }
  const int tot = v[0] + v[1] + v[2] + v[3];
  tsum[t] = tot;
  __syncthreads();
  for (int off = 1; off < 256; off <<= 1) {
    const int add = (t >= off) ? tsum[t - off] : 0;
    __syncthreads();
    tsum[t] += add;
    __syncthreads();
  }
  int run = bsums[blockIdx.x] + tsum[t] - tot;
#pragma unroll
  for (int j = 0; j < 4; ++j) {
    const int idx = base + j;
    if (idx < N) {
      row_start[idx] = run;
      run += v[j];
      const float deg = (float)(unsigned int)pk[j] * (1.0f / 16777216.0f);
      dis[idx] = rsqrtf(deg + 1.0f);
    }
  }
}

// csr[row_start[dst] + eseq[e]] = {src, norm}.  No atomics.
__global__ void fill_csr(const int* __restrict__ ei, const int* __restrict__ flag,
                         const float* __restrict__ ew, const float* __restrict__ dis,
                         const int* __restrict__ row_start, const int* __restrict__ eseq,
                         int2* __restrict__ csr, int E) {
  const int e = blockIdx.x * blockDim.x + threadIdx.x;
  if (e >= E) return;
  const int use64 = flag[0];
  const int s = use64 ? ei[2 * e] : ei[e];
  const int d = use64 ? ei[2 * (E + e)] : ei[E + e];
  const float nm = dis[s] * ew[e] * dis[d];
  const int pos = row_start[d] + eseq[e];
  csr[pos] = make_int2(s, __float_as_int(nm));
}

// C[N x M] = A[N x 128] @ B[128 x M] via 16x16x32 bf16 MFMA, LDS-free.
template <int M>
__global__ __launch_bounds__(256)
void gemm_mfma(const unsigned short* __restrict__ A, const unsigned short* __restrict__ Bt,
               unsigned short* __restrict__ C, int N) {
  const int lane = threadIdx.x & 63;
  const int m = lane & 15;
  const int q = lane >> 4;
  const int row0 = (blockIdx.x << 6) + ((threadIdx.x >> 6) << 4);

  const bool rowok = (row0 + m) < N;
  const unsigned short* arow = A + (long long)(row0 + m) * 128 + q * 8;
  bf16x8 a[4];
  const bf16x8 zf = {0, 0, 0, 0, 0, 0, 0, 0};
#pragma unroll
  for (int kt = 0; kt < 4; ++kt)
    a[kt] = rowok ? *(const bf16x8*)(arow + kt * 32) : zf;

#pragma unroll
  for (int ct = 0; ct < M / 16; ++ct) {
    f32x4 acc = {0.f, 0.f, 0.f, 0.f};
    const unsigned short* brow = Bt + (ct * 16 + m) * 128 + q * 8;
#pragma unroll
    for (int kt = 0; kt < 4; ++kt) {
      const bf16x8 b = *(const bf16x8*)(brow + kt * 32);
      acc = __builtin_amdgcn_mfma_f32_16x16x32_bf16(a[kt], b, acc, 0, 0, 0);
    }
#pragma unroll
    for (int r = 0; r < 4; ++r) {
      const int row = row0 + q * 4 + r;
      if (row < N) C[(long long)row * M + ct * 16 + m] = f2bf(acc[r]);
    }
  }
}

// One wave per dst node, TWO edges per wave (32 lanes x 8B each for M=128,
// 32 lanes x 4B for M=64). 4-pair (8-edge) unroll; cross-half shfl_xor(32)
// combines the two partial sums at the end.
template <int M, bool RELU, bool OUTBF>
__global__ __launch_bounds__(256)
void gather2(const int2* __restrict__ csr, const int* __restrict__ row_start,
             const unsigned short* __restrict__ xw, const float* __restrict__ dis,
             const float* __restrict__ bias, void* __restrict__ outp, int N) {
  const int node = (blockIdx.x << 2) + (threadIdx.x >> 6);
  const int lane = threadIdx.x & 63;
  const int half = lane >> 5;
  const int hl = lane & 31;
  if (node >= N) return;
  const int beg = __builtin_amdgcn_readfirstlane(row_start[node]);
  const int end = __builtin_amdgcn_readfirstlane(row_start[node + 1]);
  if (M == 128) {
    const int c = hl << 2;   // 4 bf16 cols per lane
    float4 A0 = make_float4(0.f, 0.f, 0.f, 0.f), A1 = A0, A2 = A0, A3 = A0;
    int e = beg;
    for (; e + 7 < end; e += 8) {
      int2 p[4];
      uint2 u[4];
#pragma unroll
      for (int j = 0; j < 4; ++j) p[j] = csr[e + 2 * j + half];
#pragma unroll
      for (int j = 0; j < 4; ++j)
        u[j] = *(const uint2*)(xw + (long long)p[j].x * 128 + c);
#pragma unroll
      for (int j = 0; j < 4; ++j) {
        const float nm = __int_as_float(p[j].y);
        float4& A = (j == 0) ? A0 : (j == 1) ? A1 : (j == 2) ? A2 : A3;
        A.x = fmaf(nm, bflo(u[j].x), A.x);
        A.y = fmaf(nm, bfhi(u[j].x), A.y);
        A.z = fmaf(nm, bflo(u[j].y), A.z);
        A.w = fmaf(nm, bfhi(u[j].y), A.w);
      }
    }
    for (; e + 1 < end; e += 2) {
      const int2 p = csr[e + half];
      const uint2 u = *(const uint2*)(xw + (long long)p.x * 128 + c);
      const float nm = __int_as_float(p.y);
      A0.x = fmaf(nm, bflo(u.x), A0.x);
      A0.y = fmaf(nm, bfhi(u.x), A0.y);
      A0.z = fmaf(nm, bflo(u.y), A0.z);
      A0.w = fmaf(nm, bfhi(u.y), A0.w);
    }
    if (e < end && half == 0) {   // single leftover edge, half 0 only
      const int2 p = csr[e];
      const uint2 u = *(const uint2*)(xw + (long long)p.x * 128 + c);
      const float nm = __int_as_float(p.y);
      A1.x = fmaf(nm, bflo(u.x), A1.x);
      A1.y = fmaf(nm, bfhi(u.x), A1.y);
      A1.z = fmaf(nm, bflo(u.y), A1.z);
      A1.w = fmaf(nm, bfhi(u.y), A1.w);
    }
    float4 acc;
    acc.x = (A0.x + A1.x) + (A2.x + A3.x);
    acc.y = (A0.y + A1.y) + (A2.y + A3.y);
    acc.z = (A0.z + A1.z) + (A2.z + A3.z);
    acc.w = (A0.w + A1.w) + (A2.w + A3.w);
    acc.x += __shfl_xor(acc.x, 32);
    acc.y += __shfl_xor(acc.y, 32);
    acc.z += __shfl_xor(acc.z, 32);
    acc.w += __shfl_xor(acc.w, 32);
    const float di = dis[node];
    const float dsq = di * di;
    const uint2 su = *(const uint2*)(xw + (long long)node * 128 + c);
    const float4 bv = *(const float4*)(bias + c);
    acc.x = fmaf(dsq, bflo(su.x), acc.x) + bv.x;
    acc.y = fmaf(dsq, bfhi(su.x), acc.y) + bv.y;
    acc.z = fmaf(dsq, bflo(su.y), acc.z) + bv.z;
    acc.w = fmaf(dsq, bfhi(su.y), acc.w) + bv.w;
    if (RELU) {
      acc.x = fmaxf(acc.x, 0.f); acc.y = fmaxf(acc.y, 0.f);
      acc.z = fmaxf(acc.z, 0.f); acc.w = fmaxf(acc.w, 0.f);
    }
    if (half == 0) {
      if (OUTBF) {
        uint2 pk;
        pk.x = (unsigned int)f2bf(acc.x) | ((unsigned int)f2bf(acc.y) << 16);
        pk.y = (unsigned int)f2bf(acc.z) | ((unsigned int)f2bf(acc.w) << 16);
        ((uint2*)outp)[(long long)node * 32 + hl] = pk;
      } else {
        *(float4*)((float*)outp + (long long)node * 128 + c) = acc;
      }
    }
  } else {
    const int c = hl << 1;   // 2 bf16 cols per lane
    float2 A0 = make_float2(0.f, 0.f), A1 = A0, A2 = A0, A3 = A0;
    int e = beg;
    for (; e + 7 < end; e += 8) {
      int2 p[4];
      unsigned int u[4];
#pragma unroll
      for (int j = 0; j < 4; ++j) p[j] = csr[e + 2 * j + half];
#pragma unroll
      for (int j = 0; j < 4; ++j)
        u[j] = *(const unsigned int*)(xw + (long long)p[j].x * 64 + c);
#pragma unroll
      for (int j = 0; j < 4; ++j) {
        const float nm = __int_as_float(p[j].y);
        float2& A = (j == 0) ? A0 : (j == 1) ? A1 : (j == 2) ? A2 : A3;
        A.x = fmaf(nm, bflo(u[j]), A.x);
        A.y = fmaf(nm, bfhi(u[j]), A.y);
      }
    }
    for (; e + 1 < end; e += 2) {
      const int2 p = csr[e + half];
      const unsigned int u = *(const unsigned int*)(xw + (long long)p.x * 64 + c);
      const float nm = __int_as_float(p.y);
      A0.x = fmaf(nm, bflo(u), A0.x);
      A0.y = fmaf(nm, bfhi(u), A0.y);
    }
    if (e < end && half == 0) {
      const int2 p = csr[e];
      const unsigned int u = *(const unsigned int*)(xw + (long long)p.x * 64 + c);
      const float nm = __int_as_float(p.y);
      A1.x = fmaf(nm, bflo(u), A1.x);
      A1.y = fmaf(nm, bfhi(u), A1.y);
    }
    float2 acc;
    acc.x = (A0.x + A1.x) + (A2.x + A3.x);
    acc.y = (A0.y + A1.y) + (A2.y + A3.y);
    acc.x += __shfl_xor(acc.x, 32);
    acc.y += __shfl_xor(acc.y, 32);
    const float di = dis[node];
    const float dsq = di * di;
    const unsigned int sv = *(const unsigned int*)(xw + (long long)node * 64 + c);
    const float2 bv = *(const float2*)(bias + c);
    acc.x = fmaf(dsq, bflo(sv), acc.x) + bv.x;
    acc.y = fmaf(dsq, bfhi(sv), acc.y) + bv.y;
    if (RELU) { acc.x = fmaxf(acc.x, 0.f); acc.y = fmaxf(acc.y, 0.f); }
    if (half == 0) {
      *(float2*)((float*)outp + (long long)node * 64 + c) = acc;
    }
  }
}

extern "C" void kernel_launch(void* const* d_in, const int* in_sizes, int n_in,
                              void* d_out, int out_size, void* d_ws, size_t ws_size,
                              hipStream_t stream) {
  const float* x  = (const float*)d_in[0];
  const int*   ei = (const int*)d_in[1];
  const float* ew = (const float*)d_in[2];
  const float* W1 = (const float*)d_in[3];
  const float* b1 = (const float*)d_in[4];
  const float* W2 = (const float*)d_in[5];
  const float* b2 = (const float*)d_in[6];
  const float* W3 = (const float*)d_in[7];
  const float* b3 = (const float*)d_in[8];
  float* out = (float*)d_out;

  const int IN = 128;
  const int N = in_sizes[0] / IN;   // 100000
  const int E = in_sizes[2];        // 1600000

  char* ws = (char*)d_ws;
  unsigned long long* packed = (unsigned long long*)(ws);
  float* dis       = (float*)(ws + (1u << 20));
  int*   flag      = (int*)(ws + (1536u << 10));
  int*   bsums     = (int*)(ws + (1536u << 10) + 4096);
  int*   row_start = (int*)(ws + (1600u << 10));
  int2*  csr       = (int2*)(ws + (2560u << 10));
  unsigned short* Wt1 = (unsigned short*)(ws + (15872u << 10));
  unsigned short* Wt2 = (unsigned short*)(ws + (15872u << 10) + (128u << 10));
  unsigned short* Wt3 = (unsigned short*)(ws + (15872u << 10) + (256u << 10));
  unsigned short* bufA = (unsigned short*)(ws + (16u << 20));   // bf16 xw
  unsigned short* hbf  = (unsigned short*)(ws + (42u << 20));   // bf16 x / h
  int* eseq = (int*)(ws + (96u << 20));   // 6.4 MB

  const dim3 blk(256);
  const int gE = (E + 255) / 256;
  const int B = (N + 1023) / 1024;
  const int gGemm = (N + 63) / 64;
  const int gGather = (N + 3) / 4;

  // --- init + operand prep (fused; all independent of the atomic chain) ---
  hipLaunchKernelGGL(init_prep, dim3(288 + 1024), blk, 0, stream,
                     ei, flag, (int*)packed, 2 * N,
                     W1, W2, W3, Wt1, Wt2, Wt3, x, hbf, (long long)N * 32);
  // --- CSR build ---
  hipLaunchKernelGGL(count_deg_pack, dim3(gE), blk, 0, stream, ei, flag, ew, packed, eseq, E);
  hipLaunchKernelGGL(scan_phase1, dim3(B), blk, 0, stream, packed, bsums, N);
  hipLaunchKernelGGL(scan_phase2, dim3(1), dim3(1024), 0, stream, bsums, row_start, B, N);
  hipLaunchKernelGGL(scan_phase3_dis, dim3(B), blk, 0, stream, packed, bsums, row_start, dis, N);
  hipLaunchKernelGGL(fill_csr, dim3(gE), blk, 0, stream, ei, flag, ew, dis, row_start, eseq, csr, E);
  // --- layer 1 ---
  hipLaunchKernelGGL((gemm_mfma<128>), dim3(gGemm), blk, 0, stream, hbf, Wt1, bufA, N);
  hipLaunchKernelGGL((gather2<128, true, true>), dim3(gGather), blk, 0, stream,
                     csr, row_start, bufA, dis, b1, hbf, N);
  // --- layer 2 ---
  hipLaunchKernelGGL((gemm_mfma<128>), dim3(gGemm), blk, 0, stream, hbf, Wt2, bufA, N);
  hipLaunchKernelGGL((gather2<128, true, true>), dim3(gGather), blk, 0, stream,
                     csr, row_start, bufA, dis, b2, hbf, N);
  // --- layer 3 ---
  hipLaunchKernelGGL((gemm_mfma<64>), dim3(gGemm), blk, 0, stream, hbf, Wt3, bufA, N);
  hipLaunchKernelGGL((gather2<64, false, false>), dim3(gGather), blk, 0, stream,
                     csr, row_start, bufA, dis, b3, out, N);
}

// Round 11
// 488.095 us; speedup vs baseline: 1.0605x; 1.0605x over previous
//
#include <hip/hip_runtime.h>

// ---------------------------------------------------------------------------
// GCN 3-layer forward. R7 structure (best: 487.7us) + unroll-16 gather stage
// + scan phase1/2 fused via last-block pattern. gather2 (R10) reverted: it
// halved per-wave MLP and regressed. d_ws layout (ws proven >= 119.2 MB):
//   [0)      packed: N u64 {hi=count, lo=fixed24 sum(ew)}   (800 KB)
//   [1 MB)   dis: N floats
//   [1.5 MB) flag: 1 int;  [1.5MB+4K) bsums: up to 1024 ints; [1.5MB+8K) ctr
//   [1.6 MB) row_start: (N+1) ints
//   [2.5 MB) csr: E x int2 {src, norm-as-int}  (12.8 MB, ends 15.3 MB)
//   [15.5MB) Wt1 bf16 [128][128]; Wt2; Wt3 [64][128]
//   [16 MB)  bufA: N*128 bf16 xw (25.6 MB; eseq E ints aliases its head)
//   [42 MB)  hbf: N*128 bf16 (x_bf16, then h1_bf16, then h2_bf16)
// ---------------------------------------------------------------------------

typedef __attribute__((ext_vector_type(8))) short bf16x8;
typedef __attribute__((ext_vector_type(4))) float f32x4;

__device__ inline unsigned short f2bf(float f) {   // RNE f32 -> bf16
  unsigned int u = __float_as_uint(f);
  u += 0x7fffu + ((u >> 16) & 1u);
  return (unsigned short)(u >> 16);
}
__device__ inline float bflo(unsigned int u) { return __uint_as_float(u << 16); }
__device__ inline float bfhi(unsigned int u) { return __uint_as_float(u & 0xffff0000u); }

// Block 0: detect int64 edge layout + zero scan counter. All: zero packed.
__global__ void init_kernel(const int* __restrict__ ei, int* __restrict__ flag,
                            int* __restrict__ ctr, int* __restrict__ pz, int n) {
  if (blockIdx.x == 0) {
    __shared__ int nonzero;
    if (threadIdx.x == 0) { nonzero = 0; ctr[0] = 0; }
    __syncthreads();
    int acc = 0;
#pragma unroll
    for (int it = 0; it < 8; ++it) acc |= ei[2 * (threadIdx.x + (it << 8)) + 1];
    if (acc != 0) atomicOr(&nonzero, 1);
    __syncthreads();
    if (threadIdx.x == 0) flag[0] = (nonzero == 0) ? 1 : 0;
  }
  int i = blockIdx.x * blockDim.x + threadIdx.x;
  const int stride = gridDim.x * blockDim.x;
  for (; i < n; i += stride) pz[i] = 0;
}

// One packed u64 atomic per edge: hi += 1 (count), lo += ew * 2^24 (deg).
__global__ void count_deg_pack(const int* __restrict__ ei, const int* __restrict__ flag,
                               const float* __restrict__ ew,
                               unsigned long long* __restrict__ packed,
                               int* __restrict__ eseq, int E) {
  const int e = blockIdx.x * blockDim.x + threadIdx.x;
  if (e >= E) return;
  const int use64 = flag[0];
  const int d = use64 ? ei[2 * (E + e)] : ei[E + e];
  const unsigned int fx = (unsigned int)(ew[e] * 16777216.0f);  // 2^24 fixed
  const unsigned long long old =
      atomicAdd(&packed[d], (1ULL << 32) | (unsigned long long)fx);
  eseq[e] = (int)(old >> 32);
}

// Fused scan phases 1+2: every block reduces its 1024-chunk; the LAST block
// to finish (device-scope counter) exclusive-scans the partials.
__global__ __launch_bounds__(256)
void scan12(const unsigned long long* __restrict__ packed, int* __restrict__ bsums,
            int* __restrict__ row_start, int* __restrict__ ctr, int B, int N) {
  __shared__ int red[256];
  __shared__ int amLast;
  const int t = threadIdx.x;
  {
    const int base = blockIdx.x * 1024 + t * 4;
    int s = 0;
#pragma unroll
    for (int j = 0; j < 4; ++j) {
      const int idx = base + j;
      if (idx < N) s += (int)(packed[idx] >> 32);
    }
    red[t] = s;
  }
  __syncthreads();
  for (int off = 128; off > 0; off >>= 1) {
    if (t < off) red[t] += red[t + off];
    __syncthreads();
  }
  if (t == 0) {
    bsums[blockIdx.x] = red[0];
    __threadfence();
    amLast = (atomicAdd(ctr, 1) == B - 1) ? 1 : 0;
  }
  __syncthreads();
  if (!amLast) return;
  // exclusive scan of bsums[0..B) (B <= 1024), coherent re-read via atomic RMW
  int v[4];
#pragma unroll
  for (int j = 0; j < 4; ++j) {
    const int idx = t * 4 + j;
    v[j] = (idx < B) ? atomicAdd(&bsums[idx], 0) : 0;
  }
  const int tot = v[0] + v[1] + v[2] + v[3];
  red[t] = tot;
  __syncthreads();
  for (int off = 1; off < 256; off <<= 1) {
    const int add = (t >= off) ? red[t - off] : 0;
    __syncthreads();
    red[t] += add;
    __syncthreads();
  }
  int run = red[t] - tot;   // grid-wide exclusive prefix of this thread's chunk
#pragma unroll
  for (int j = 0; j < 4; ++j) {
    const int idx = t * 4 + j;
    if (idx < B) { bsums[idx] = run; run += v[j]; }
  }
  if (t == 255) row_start[N] = red[255];
}

// Phase 3 + dis = rsqrt(deg+1) fused.
__global__ __launch_bounds__(256)
void scan_phase3_dis(const unsigned long long* __restrict__ packed,
                     const int* __restrict__ bsums, int* __restrict__ row_start,
                     float* __restrict__ dis, int N) {
  __shared__ int tsum[256];
  const int t = threadIdx.x;
  const int base = blockIdx.x * 1024 + t * 4;
  unsigned long long pk[4];
  int v[4];
#pragma unroll
  for (int j = 0; j < 4; ++j) {
    pk[j] = (base + j < N) ? packed[base + j] : 0ULL;
    v[j] = (int)(pk[j] >> 32);
  }
  const int tot = v[0] + v[1] + v[2] + v[3];
  tsum[t] = tot;
  __syncthreads();
  for (int off = 1; off < 256; off <<= 1) {
    const int add = (t >= off) ? tsum[t - off] : 0;
    __syncthreads();
    tsum[t] += add;
    __syncthreads();
  }
  int run = bsums[blockIdx.x] + tsum[t] - tot;
#pragma unroll
  for (int j = 0; j < 4; ++j) {
    const int idx = base + j;
    if (idx < N) {
      row_start[idx] = run;
      run += v[j];
      const float deg = (float)(unsigned int)pk[j] * (1.0f / 16777216.0f);
      dis[idx] = rsqrtf(deg + 1.0f);
    }
  }
}

// csr[row_start[dst] + eseq[e]] = {src, norm}.  No atomics.
__global__ void fill_csr(const int* __restrict__ ei, const int* __restrict__ flag,
                         const float* __restrict__ ew, const float* __restrict__ dis,
                         const int* __restrict__ row_start, const int* __restrict__ eseq,
                         int2* __restrict__ csr, int E) {
  const int e = blockIdx.x * blockDim.x + threadIdx.x;
  if (e >= E) return;
  const int use64 = flag[0];
  const int s = use64 ? ei[2 * e] : ei[e];
  const int d = use64 ? ei[2 * (E + e)] : ei[E + e];
  const float nm = dis[s] * ew[e] * dis[d];
  const int pos = row_start[d] + eseq[e];
  csr[pos] = make_int2(s, __float_as_int(nm));
}

// Fused operand prep: blocks [0,160) transpose+convert W1/W2/W3; rest convert x.
__global__ __launch_bounds__(256)
void prep_bf16(const float* __restrict__ W1, const float* __restrict__ W2,
               const float* __restrict__ W3, unsigned short* __restrict__ Wt1,
               unsigned short* __restrict__ Wt2, unsigned short* __restrict__ Wt3,
               const float* __restrict__ x, unsigned short* __restrict__ xbf,
               long long n4) {
  const int WTB = 160;
  if (blockIdx.x < WTB) {
    const int idx = blockIdx.x * 256 + threadIdx.x;
    if (idx < 16384) {
      const int m = idx >> 7, k = idx & 127;
      Wt1[idx] = f2bf(W1[k * 128 + m]);
    } else if (idx < 32768) {
      const int l = idx - 16384;
      const int m = l >> 7, k = l & 127;
      Wt2[l] = f2bf(W2[k * 128 + m]);
    } else {
      const int l = idx - 32768;
      const int m = l >> 7, k = l & 127;
      Wt3[l] = f2bf(W3[k * 64 + m]);
    }
    return;
  }
  long long i = (long long)(blockIdx.x - WTB) * 256 + threadIdx.x;
  const long long stride = (long long)(gridDim.x - WTB) * 256;
  for (; i < n4; i += stride) {
    const float4 v = ((const float4*)x)[i];
    ushort4 o;
    o.x = f2bf(v.x); o.y = f2bf(v.y); o.z = f2bf(v.z); o.w = f2bf(v.w);
    ((ushort4*)xbf)[i] = o;
  }
}

// C[N x M] = A[N x 128] @ B[128 x M] via 16x16x32 bf16 MFMA, LDS-free.
template <int M>
__global__ __launch_bounds__(256)
void gemm_mfma(const unsigned short* __restrict__ A, const unsigned short* __restrict__ Bt,
               unsigned short* __restrict__ C, int N) {
  const int lane = threadIdx.x & 63;
  const int m = lane & 15;
  const int q = lane >> 4;
  const int row0 = (blockIdx.x << 6) + ((threadIdx.x >> 6) << 4);

  const bool rowok = (row0 + m) < N;
  const unsigned short* arow = A + (long long)(row0 + m) * 128 + q * 8;
  bf16x8 a[4];
  const bf16x8 zf = {0, 0, 0, 0, 0, 0, 0, 0};
#pragma unroll
  for (int kt = 0; kt < 4; ++kt)
    a[kt] = rowok ? *(const bf16x8*)(arow + kt * 32) : zf;

#pragma unroll
  for (int ct = 0; ct < M / 16; ++ct) {
    f32x4 acc = {0.f, 0.f, 0.f, 0.f};
    const unsigned short* brow = Bt + (ct * 16 + m) * 128 + q * 8;
#pragma unroll
    for (int kt = 0; kt < 4; ++kt) {
      const bf16x8 b = *(const bf16x8*)(brow + kt * 32);
      acc = __builtin_amdgcn_mfma_f32_16x16x32_bf16(a[kt], b, acc, 0, 0, 0);
    }
#pragma unroll
    for (int r = 0; r < 4; ++r) {
      const int row = row0 + q * 4 + r;
      if (row < N) C[(long long)row * M + ct * 16 + m] = f2bf(acc[r]);
    }
  }
}

// One wave per dst node, 16-way then 8/2/1 edge unroll, wave-uniform (scalar)
// CSR descriptor reads; one 4B bf16x2 row-load per lane per edge.
template <int M, bool RELU, bool OUTBF>
__global__ __launch_bounds__(256)
void gather(const int2* __restrict__ csr, const int* __restrict__ row_start,
            const unsigned short* __restrict__ xw, const float* __restrict__ dis,
            const float* __restrict__ bias, void* __restrict__ outp, int N) {
  const int node = (blockIdx.x << 2) + (threadIdx.x >> 6);
  const int lane = threadIdx.x & 63;
  if (node >= N) return;
  const int beg = __builtin_amdgcn_readfirstlane(row_start[node]);
  const int end = __builtin_amdgcn_readfirstlane(row_start[node + 1]);
  if (M == 128) {
    const int c = lane << 1;
    float2 a0 = make_float2(0.f, 0.f), a1 = a0, a2 = a0, a3 = a0;
    int e = beg;
    for (; e + 15 < end; e += 16) {   // 16 outstanding row-loads per lane
      int2 p[16];
      unsigned int u[16];
#pragma unroll
      for (int j = 0; j < 16; ++j) p[j] = csr[e + j];
#pragma unroll
      for (int j = 0; j < 16; ++j)
        u[j] = *(const unsigned int*)(xw + (long long)p[j].x * 128 + c);
#pragma unroll
      for (int j = 0; j < 16; ++j) {
        const float nm = __int_as_float(p[j].y);
        float2& ac = (j & 2) ? ((j & 1) ? a3 : a2) : ((j & 1) ? a1 : a0);
        ac.x = fmaf(nm, bflo(u[j]), ac.x);
        ac.y = fmaf(nm, bfhi(u[j]), ac.y);
      }
    }
    for (; e + 7 < end; e += 8) {
      int2 p[8];
      unsigned int u[8];
#pragma unroll
      for (int j = 0; j < 8; ++j) p[j] = csr[e + j];
#pragma unroll
      for (int j = 0; j < 8; ++j)
        u[j] = *(const unsigned int*)(xw + (long long)p[j].x * 128 + c);
#pragma unroll
      for (int j = 0; j < 8; ++j) {
        const float nm = __int_as_float(p[j].y);
        float2& ac = (j & 4) ? ((j & 2) ? a3 : a2) : ((j & 2) ? a1 : a0);
        ac.x = fmaf(nm, bflo(u[j]), ac.x);
        ac.y = fmaf(nm, bfhi(u[j]), ac.y);
      }
    }
    for (; e + 1 < end; e += 2) {
      const int2 p0 = csr[e], p1 = csr[e + 1];
      const unsigned int u0 = *(const unsigned int*)(xw + (long long)p0.x * 128 + c);
      const unsigned int u1 = *(const unsigned int*)(xw + (long long)p1.x * 128 + c);
      const float n0 = __int_as_float(p0.y), n1 = __int_as_float(p1.y);
      a0.x = fmaf(n0, bflo(u0), a0.x);
      a0.y = fmaf(n0, bfhi(u0), a0.y);
      a1.x = fmaf(n1, bflo(u1), a1.x);
      a1.y = fmaf(n1, bfhi(u1), a1.y);
    }
    if (e < end) {
      const int2 p = csr[e];
      const float nm = __int_as_float(p.y);
      const unsigned int u = *(const unsigned int*)(xw + (long long)p.x * 128 + c);
      a2.x = fmaf(nm, bflo(u), a2.x);
      a2.y = fmaf(nm, bfhi(u), a2.y);
    }
    float2 acc;
    acc.x = (a0.x + a1.x) + (a2.x + a3.x);
    acc.y = (a0.y + a1.y) + (a2.y + a3.y);
    const float di = dis[node];
    const float dsq = di * di;
    const unsigned int su = *(const unsigned int*)(xw + (long long)node * 128 + c);
    const float2 bv = *(const float2*)(bias + c);
    acc.x = fmaf(dsq, bflo(su), acc.x) + bv.x;
    acc.y = fmaf(dsq, bfhi(su), acc.y) + bv.y;
    if (RELU) { acc.x = fmaxf(acc.x, 0.f); acc.y = fmaxf(acc.y, 0.f); }
    if (OUTBF) {
      const unsigned int pk =
          (unsigned int)f2bf(acc.x) | ((unsigned int)f2bf(acc.y) << 16);
      ((unsigned int*)outp)[(long long)node * 64 + lane] = pk;
    } else {
      *(float2*)((float*)outp + (long long)node * 128 + c) = acc;
    }
  } else {
    float a0 = 0.f, a1 = 0.f, a2 = 0.f, a3 = 0.f;
    int e = beg;
    for (; e + 7 < end; e += 8) {
      int2 p[8];
      unsigned int v[8];
#pragma unroll
      for (int j = 0; j < 8; ++j) p[j] = csr[e + j];
#pragma unroll
      for (int j = 0; j < 8; ++j) v[j] = xw[(long long)p[j].x * 64 + lane];
#pragma unroll
      for (int j = 0; j < 8; ++j) {
        float& ac = (j & 4) ? ((j & 2) ? a3 : a2) : ((j & 2) ? a1 : a0);
        ac = fmaf(__int_as_float(p[j].y), bflo(v[j]), ac);
      }
    }
    for (; e < end; ++e) {
      const int2 p = csr[e];
      const unsigned int v = xw[(long long)p.x * 64 + lane];
      a0 = fmaf(__int_as_float(p.y), bflo(v), a0);
    }
    float acc = (a0 + a1) + (a2 + a3);
    const float di = dis[node];
    const unsigned int sv = xw[(long long)node * 64 + lane];
    float r = fmaf(di * di, bflo(sv), acc) + bias[lane];
    if (RELU) r = fmaxf(r, 0.f);
    ((float*)outp)[(long long)node * 64 + lane] = r;
  }
}

extern "C" void kernel_launch(void* const* d_in, const int* in_sizes, int n_in,
                              void* d_out, int out_size, void* d_ws, size_t ws_size,
                              hipStream_t stream) {
  const float* x  = (const float*)d_in[0];
  const int*   ei = (const int*)d_in[1];
  const float* ew = (const float*)d_in[2];
  const float* W1 = (const float*)d_in[3];
  const float* b1 = (const float*)d_in[4];
  const float* W2 = (const float*)d_in[5];
  const float* b2 = (const float*)d_in[6];
  const float* W3 = (const float*)d_in[7];
  const float* b3 = (const float*)d_in[8];
  float* out = (float*)d_out;

  const int IN = 128;
  const int N = in_sizes[0] / IN;   // 100000
  const int E = in_sizes[2];        // 1600000

  char* ws = (char*)d_ws;
  unsigned long long* packed = (unsigned long long*)(ws);
  float* dis       = (float*)(ws + (1u << 20));
  int*   flag      = (int*)(ws + (1536u << 10));
  int*   bsums     = (int*)(ws + (1536u << 10) + 4096);
  int*   ctr       = (int*)(ws + (1536u << 10) + 8192);
  int*   row_start = (int*)(ws + (1600u << 10));
  int2*  csr       = (int2*)(ws + (2560u << 10));
  unsigned short* Wt1 = (unsigned short*)(ws + (15872u << 10));
  unsigned short* Wt2 = (unsigned short*)(ws + (15872u << 10) + (128u << 10));
  unsigned short* Wt3 = (unsigned short*)(ws + (15872u << 10) + (256u << 10));
  unsigned short* bufA = (unsigned short*)(ws + (16u << 20));   // bf16 xw
  unsigned short* hbf  = (unsigned short*)(ws + (42u << 20));   // bf16 x / h
  int* eseq = (int*)bufA;   // dead before GEMM1 writes bufA

  const dim3 blk(256);
  const int gE = (E + 255) / 256;
  const int B = (N + 1023) / 1024;
  const int gGemm = (N + 63) / 64;
  const int gGather = (N + 3) / 4;

  // --- CSR build + normalization coefficients ---
  hipLaunchKernelGGL(init_kernel, dim3(128), blk, 0, stream, ei, flag, ctr, (int*)packed, 2 * N);
  hipLaunchKernelGGL(count_deg_pack, dim3(gE), blk, 0, stream, ei, flag, ew, packed, eseq, E);
  hipLaunchKernelGGL(scan12, dim3(B), blk, 0, stream, packed, bsums, row_start, ctr, B, N);
  hipLaunchKernelGGL(scan_phase3_dis, dim3(B), blk, 0, stream, packed, bsums, row_start, dis, N);
  hipLaunchKernelGGL(fill_csr, dim3(gE), blk, 0, stream, ei, flag, ew, dis, row_start, eseq, csr, E);
  hipLaunchKernelGGL(prep_bf16, dim3(160 + 2048), blk, 0, stream,
                     W1, W2, W3, Wt1, Wt2, Wt3, x, hbf, (long long)N * 32);

  // --- layer 1 ---
  hipLaunchKernelGGL((gemm_mfma<128>), dim3(gGemm), blk, 0, stream, hbf, Wt1, bufA, N);
  hipLaunchKernelGGL((gather<128, true, true>), dim3(gGather), blk, 0, stream,
                     csr, row_start, bufA, dis, b1, hbf, N);
  // --- layer 2 ---
  hipLaunchKernelGGL((gemm_mfma<128>), dim3(gGemm), blk, 0, stream, hbf, Wt2, bufA, N);
  hipLaunchKernelGGL((gather<128, true, true>), dim3(gGather), blk, 0, stream,
                     csr, row_start, bufA, dis, b2, hbf, N);
  // --- layer 3 ---
  hipLaunchKernelGGL((gemm_mfma<64>), dim3(gGemm), blk, 0, stream, hbf, Wt3, bufA, N);
  hipLaunchKernelGGL((gather<64, false, false>), dim3(gGather), blk, 0, stream,
                     csr, row_start, bufA, dis, b3, out, N);
}